// Round 15
// baseline (133.313 us; speedup 1.0000x reference)
//
#include <hip/hip_runtime.h>
#include <hip/hip_bf16.h>
#include <math.h>

#define N_NODES 50000
#define E_EDGES 800000
#define IN_DIM  128
#define HID     64
#define KF      4
#define EXP_HID 64

// d_out layout (float32, concatenated in return order):
//   disen_graph_emb (K*HID = 256) | Z (N*K*HID = 12,800,000) |
//   e_h_final (E = 800,000)       | e_h_all (K*E = 3,200,000)
#define OFF_DISEN 0
#define OFF_Z     (KF*HID)
#define OFF_EHF   (OFF_Z + N_NODES*KF*HID)
#define OFF_EHALL (OFF_EHF + E_EDGES)

#define NROWS (N_NODES * KF)     // 200000 (n,k) rows
#define EPW 64                   // edges per wave in edge_kernel6

typedef __bf16 bf16x8 __attribute__((ext_vector_type(8)));
typedef float  f32x4  __attribute__((ext_vector_type(4)));
typedef unsigned short ushort_t;
typedef unsigned int   uint_t;

// ---------------------------------------------------------------------------
// prep (r12 verbatim): 41 blocks. 0-31: Wz swizzle; 32-39: Wpq swizzle;
// 40: disen init.
// ---------------------------------------------------------------------------
__global__ __launch_bounds__(256) void prep_kernel(
    const float* __restrict__ W, const float* __restrict__ W1,
    float* __restrict__ disen, __bf16* __restrict__ Wz,
    __bf16* __restrict__ Wpq) {
  const int b = blockIdx.x, tid = threadIdx.x;
  if (b < 32) {
#pragma unroll
    for (int i = 0; i < 4; ++i) {
      const int idx = (b * 4 + i) * 256 + tid;    // k*8192 + ii*64 + h
      const int k  = idx >> 13;
      const int ii = (idx >> 6) & 127;
      const int h  = idx & 63;
      const int col = k * 64 + h;
      const int t = col >> 4, c = col & 15;
      const int kh = ii >> 5, g = (ii >> 3) & 3, e = ii & 7;
      Wz[((t * 4 + kh) * 4 + g) * 128 + c * 8 + e] = (__bf16)W[idx];
    }
  } else if (b < 40) {
#pragma unroll
    for (int i = 0; i < 4; ++i) {
      const int idx = ((b - 32) * 4 + i) * 256 + tid;   // r*64 + cc
      const int r = idx >> 6, cc = idx & 63;
      const int k = (r < 64) ? r : (r - 64);
      const int j = (r < 64) ? cc : (64 + cc);
      const int t = j >> 4, c = j & 15;
      const int kh = k >> 5, g = (k >> 3) & 3, e = k & 7;
      Wpq[((t * 2 + kh) * 4 + g) * 128 + c * 8 + e] = (__bf16)W1[idx];
    }
  } else {
    disen[tid] = 0.f;
  }
}

// ---------------------------------------------------------------------------
// z via MFMA (r13 verbatim, k-phased). Measured-good.
// ---------------------------------------------------------------------------
__global__ __launch_bounds__(256) void z_mfma_kernel2(
    const float* __restrict__ x, const float* __restrict__ b_init,
    const __bf16* __restrict__ Wz, float* __restrict__ out) {
  __shared__ float dred[4][256];
  const int tid = threadIdx.x;
  const int w = tid >> 6, l = tid & 63;
  const int lg = l >> 4, lc = l & 15;
  const int n0 = blockIdx.x * 64;
  const int ra = min(n0 + w * 16 + lc, N_NODES - 1);   // A row (clamped tail)

  bf16x8 af[4];
#pragma unroll
  for (int kh = 0; kh < 4; ++kh) {
    const float4* xp = (const float4*)(x + (size_t)ra * IN_DIM + kh * 32 + lg * 8);
    const float4 f0 = xp[0], f1 = xp[1];
    bf16x8 a;
    a[0] = (__bf16)f0.x; a[1] = (__bf16)f0.y;
    a[2] = (__bf16)f0.z; a[3] = (__bf16)f0.w;
    a[4] = (__bf16)f1.x; a[5] = (__bf16)f1.y;
    a[6] = (__bf16)f1.z; a[7] = (__bf16)f1.w;
    af[kh] = a;
  }

#pragma unroll 1
  for (int k = 0; k < KF; ++k) {
    f32x4 acc[4];
#pragma unroll
    for (int tt = 0; tt < 4; ++tt) acc[tt] = (f32x4){0.f, 0.f, 0.f, 0.f};

#pragma unroll
    for (int tt = 0; tt < 4; ++tt)
#pragma unroll
      for (int kh = 0; kh < 4; ++kh) {
        const bf16x8 bf = *(const bf16x8*)(
            Wz + (((k * 4 + tt) * 4 + kh) * 4 + lg) * 128 + lc * 8);
        acc[tt] = __builtin_amdgcn_mfma_f32_16x16x32_bf16(af[kh], bf, acc[tt],
                                                          0, 0, 0);
      }

    float vals[4][4];
#pragma unroll
    for (int tt = 0; tt < 4; ++tt) {
      const float bias = b_init[(k * 4 + tt) * 16 + lc];
#pragma unroll
      for (int r = 0; r < 4; ++r)
        vals[tt][r] = fmaxf(acc[tt][r] + bias, 0.f);
    }
    float s[4];
#pragma unroll
    for (int r = 0; r < 4; ++r)
      s[r] = vals[0][r] * vals[0][r] + vals[1][r] * vals[1][r] +
             vals[2][r] * vals[2][r] + vals[3][r] * vals[3][r];
#pragma unroll
    for (int d = 1; d < 16; d <<= 1)
#pragma unroll
      for (int r = 0; r < 4; ++r) s[r] += __shfl_xor(s[r], d, 64);
    float rn[4];
#pragma unroll
    for (int r = 0; r < 4; ++r)
      rn[r] = 1.f / fmaxf(sqrtf(s[r]), 1e-12f);

#pragma unroll
    for (int tt = 0; tt < 4; ++tt) {
      const int col = k * 64 + tt * 16 + lc;
      float dmt = 0.f;
#pragma unroll
      for (int r = 0; r < 4; ++r) {
        const float zn = vals[tt][r] * rn[r];
        const int node = n0 + w * 16 + lg * 4 + r;
        if (node < N_NODES)
          out[OFF_Z + (size_t)node * (KF * HID) + col] = zn;
        dmt = fmaxf(dmt, zn);
      }
      dmt = fmaxf(dmt, __shfl_xor(dmt, 16, 64));
      dmt = fmaxf(dmt, __shfl_xor(dmt, 32, 64));
      if (lg == 0) dred[w][col] = dmt;
    }
  }
  __syncthreads();
  {
    const float m = fmaxf(fmaxf(dred[0][tid], dred[1][tid]),
                          fmaxf(dred[2][tid], dred[3][tid]));
    atomicMax((unsigned int*)(out + OFF_DISEN + tid), __float_as_uint(m));
  }
}

// ---------------------------------------------------------------------------
// pq via MFMA -> BIASED-uint8 P/Q with per-row scales. Same quantization
// grid as r14 (same rint, same scale; +128 bias is exact) -> absmax
// unchanged. Biased storage lets the edge kernel unpack with single-op
// v_cvt_f32_ubyteN instead of bfe+cvt (the r14 VALU bottleneck).
// Row layout byte[lc*4+t] = col[t*16+lc] (fixed permutation; W2 matched).
// ---------------------------------------------------------------------------
__global__ __launch_bounds__(256) void pq_mfma_kernel3(
    const float* __restrict__ Z, const float* __restrict__ b1,
    const __bf16* __restrict__ Wpq, unsigned char* __restrict__ P8,
    unsigned char* __restrict__ Q8, float* __restrict__ Psc,
    float* __restrict__ Qsc) {
  const int tid = threadIdx.x;
  const int w = tid >> 6, l = tid & 63;
  const int lg = l >> 4, lc = l & 15;
  const int base = blockIdx.x * 64;              // exact: 3125*64 = 200000
  const int rowA = base + w * 16 + lc;

  bf16x8 af[2];
#pragma unroll
  for (int kh = 0; kh < 2; ++kh) {
    const float4* zp = (const float4*)(Z + (size_t)rowA * HID + kh * 32 + lg * 8);
    const float4 f0 = zp[0], f1 = zp[1];
    bf16x8 a;
    a[0] = (__bf16)f0.x; a[1] = (__bf16)f0.y;
    a[2] = (__bf16)f0.z; a[3] = (__bf16)f0.w;
    a[4] = (__bf16)f1.x; a[5] = (__bf16)f1.y;
    a[6] = (__bf16)f1.z; a[7] = (__bf16)f1.w;
    af[kh] = a;
  }

  f32x4 acc[8];
#pragma unroll
  for (int t = 0; t < 8; ++t) acc[t] = (f32x4){0.f, 0.f, 0.f, 0.f};

#pragma unroll
  for (int t = 0; t < 8; ++t)
#pragma unroll
    for (int kh = 0; kh < 2; ++kh) {
      const bf16x8 bf =
          *(const bf16x8*)(Wpq + ((t * 2 + kh) * 4 + lg) * 128 + lc * 8);
      acc[t] = __builtin_amdgcn_mfma_f32_16x16x32_bf16(af[kh], bf, acc[t],
                                                       0, 0, 0);
    }

  float pvv[4][4], qvv[4][4];
#pragma unroll
  for (int t = 0; t < 4; ++t) {
    const float bias = b1[t * 16 + lc];
#pragma unroll
    for (int r = 0; r < 4; ++r) {
      pvv[t][r] = acc[t][r] + bias;
      qvv[t][r] = acc[t + 4][r];
    }
  }

#pragma unroll
  for (int r = 0; r < 4; ++r) {
    float pm = fmaxf(fmaxf(fabsf(pvv[0][r]), fabsf(pvv[1][r])),
                     fmaxf(fabsf(pvv[2][r]), fabsf(pvv[3][r])));
    float qm = fmaxf(fmaxf(fabsf(qvv[0][r]), fabsf(qvv[1][r])),
                     fmaxf(fabsf(qvv[2][r]), fabsf(qvv[3][r])));
#pragma unroll
    for (int d = 1; d < 16; d <<= 1) {           // 16-lane row reduce
      pm = fmaxf(pm, __shfl_xor(pm, d, 64));
      qm = fmaxf(qm, __shfl_xor(qm, d, 64));
    }
    pm = fmaxf(pm, 1e-12f);
    qm = fmaxf(qm, 1e-12f);
    const float pinv = 127.f / pm, qinv = 127.f / qm;

    uint_t packP = 0, packQ = 0;
#pragma unroll
    for (int t = 0; t < 4; ++t) {
      const int qp = __float2int_rn(pvv[t][r] * pinv) + 128;  // biased uint8
      const int qq = __float2int_rn(qvv[t][r] * qinv) + 128;
      packP |= (uint_t)(qp & 0xff) << (8 * t);
      packQ |= (uint_t)(qq & 0xff) << (8 * t);
    }
    const int grow = base + w * 16 + lg * 4 + r;
    *(uint_t*)(P8 + (size_t)grow * 64 + lc * 4) = packP;
    *(uint_t*)(Q8 + (size_t)grow * 64 + lc * 4) = packQ;
    if (lc == 0) {
      Psc[grow] = pm * (1.f / 127.f);
      Qsc[grow] = qm * (1.f / 127.f);
    }
  }
}

// ---------------------------------------------------------------------------
// Edge kernel v6 (biased uint8): r14 structure; unpack via
// (float)((p>>8)&0xff) -> single v_cvt_f32_ubyteN; bias folded into
// c = -128*(ps+qs) per pair (amortized over 4 elements). Per-element VALU
// 8 -> ~6.3 ops; VALU floor ~65us < fetch floor ~73us.
// ---------------------------------------------------------------------------
__global__ __launch_bounds__(256) void edge_kernel6(
    const int* __restrict__ ei, const float* __restrict__ W2,
    const float* __restrict__ b2, const unsigned char* __restrict__ P8,
    const unsigned char* __restrict__ Q8, const float* __restrict__ Psc,
    const float* __restrict__ Qsc, float* __restrict__ ehf,
    float* __restrict__ ehall) {
  __shared__ float tile[4][KF][EPW + 1];           // pad: k-stride 65
  const int tid = threadIdx.x;
  const int w = tid >> 6;
  const int lane = tid & 63;
  const int lc = lane & 15, lk = lane >> 4;
  const int eb = blockIdx.x * 256 + w * EPW;       // this wave's 64 edges

  // lane's 4 W2 coefs for orig cols {t*16+lc}
  const float w2a = W2[lc],      w2b = W2[16 + lc];
  const float w2c = W2[32 + lc], w2d = W2[48 + lc];
  const float bias2 = b2[0];

  const int srcl = ei[eb + lane];                  // coalesced
  const int dstl = ei[E_EDGES + eb + lane];

  uint_t pv[4], qv[4];
  float ps[4], qs[4];
#pragma unroll
  for (int d = 0; d < 4; ++d) {
    const int s = __shfl(srcl, d, 64);             // readlane -> SGPR base
    const int t = __shfl(dstl, d, 64);
    pv[d] = *(const uint_t*)(P8 + (size_t)s * 256 + lane * 4);
    qv[d] = *(const uint_t*)(Q8 + (size_t)t * 256 + lane * 4);
    ps[d] = Psc[s * 4 + lk];
    qs[d] = Qsc[t * 4 + lk];
  }

#pragma unroll
  for (int i = 0; i < EPW; ++i) {
    const uint_t p = pv[i & 3], q = qv[i & 3];
    const float pss = ps[i & 3], qss = qs[i & 3];
    if (i + 4 < EPW) {                             // static under full unroll
      const int s = __shfl(srcl, i + 4, 64);
      const int t = __shfl(dstl, i + 4, 64);
      pv[i & 3] = *(const uint_t*)(P8 + (size_t)s * 256 + lane * 4);
      qv[i & 3] = *(const uint_t*)(Q8 + (size_t)t * 256 + lane * 4);
      ps[i & 3] = Psc[s * 4 + lk];
      qs[i & 3] = Qsc[t * 4 + lk];
    }
    const float c = -128.f * (pss + qss);          // bias fold, 2 ops/4 elems

    // ubyte unpack: single v_cvt_f32_ubyteN each
    const float p0 = (float)(p & 0xffu);
    const float p1 = (float)((p >> 8) & 0xffu);
    const float p2 = (float)((p >> 16) & 0xffu);
    const float p3 = (float)(p >> 24);
    const float q0 = (float)(q & 0xffu);
    const float q1 = (float)((q >> 8) & 0xffu);
    const float q2 = (float)((q >> 16) & 0xffu);
    const float q3 = (float)(q >> 24);

    float s4 = fmaxf(fmaf(p0, pss, fmaf(q0, qss, c)), 0.f) * w2a;
    s4 = fmaf(fmaxf(fmaf(p1, pss, fmaf(q1, qss, c)), 0.f), w2b, s4);
    s4 = fmaf(fmaxf(fmaf(p2, pss, fmaf(q2, qss, c)), 0.f), w2c, s4);
    s4 = fmaf(fmaxf(fmaf(p3, pss, fmaf(q3, qss, c)), 0.f), w2d, s4);

    // sum the 16 lanes of this k-group
    s4 += __shfl_xor(s4, 1, 64);
    s4 += __shfl_xor(s4, 2, 64);
    s4 += __shfl_xor(s4, 4, 64);
    s4 += __shfl_xor(s4, 8, 64);
    if (lc == 0) tile[w][lk][i] = s4 + bias2;
  }
  __syncthreads();

  const float v0 = tile[w][0][lane];
  const float v1 = tile[w][1][lane];
  const float v2 = tile[w][2][lane];
  const float v3 = tile[w][3][lane];
  ehall[(size_t)0 * E_EDGES + eb + lane] = v0;     // coalesced per wave
  ehall[(size_t)1 * E_EDGES + eb + lane] = v1;
  ehall[(size_t)2 * E_EDGES + eb + lane] = v2;
  ehall[(size_t)3 * E_EDGES + eb + lane] = v3;
  ehf[eb + lane] = fmaxf(fmaxf(v0, v1), fmaxf(v2, v3));
}

// ---------------------------------------------------------------------------
extern "C" void kernel_launch(void* const* d_in, const int* in_sizes, int n_in,
                              void* d_out, int out_size, void* d_ws,
                              size_t ws_size, hipStream_t stream) {
  const float* x      = (const float*)d_in[0];
  const int*   ei     = (const int*)  d_in[1];
  const float* W_init = (const float*)d_in[2];
  const float* b_init = (const float*)d_in[3];
  const float* W1     = (const float*)d_in[4];
  const float* b1     = (const float*)d_in[5];
  const float* W2     = (const float*)d_in[6];
  const float* b2     = (const float*)d_in[7];
  float* out = (float*)d_out;

  // d_ws: P8 (12.8MB) | Q8 (12.8MB) | Psc (0.8MB) | Qsc (0.8MB) |
  //       Wz (64KB) | Wpq (16KB).  Total ~27.3MB << ws_size.
  unsigned char* P8 = (unsigned char*)d_ws;
  unsigned char* Q8 = P8 + (size_t)NROWS * 64;
  float* Psc = (float*)(Q8 + (size_t)NROWS * 64);
  float* Qsc = Psc + NROWS;
  __bf16* Wz  = (__bf16*)(Qsc + NROWS);
  __bf16* Wpq = Wz + 32768;

  prep_kernel<<<41, 256, 0, stream>>>(W_init, W1, out + OFF_DISEN, Wz, Wpq);
  z_mfma_kernel2<<<(N_NODES + 63) / 64, 256, 0, stream>>>(
      x, b_init, Wz, out);
  pq_mfma_kernel3<<<NROWS / 64, 256, 0, stream>>>(
      out + OFF_Z, b1, Wpq, P8, Q8, Psc, Qsc);
  edge_kernel6<<<E_EDGES / 256, 256, 0, stream>>>(
      ei, W2, b2, P8, Q8, Psc, Qsc, out + OFF_EHF, out + OFF_EHALL);
}